// Round 1
// baseline (781.627 us; speedup 1.0000x reference)
//
#include <hip/hip_runtime.h>

#define NN 50000
#define NE 600000
#define HD 128
#define NL 4
#define NB 256
#define NO 10
#define BN_EPS 1e-5f

// ---------------- CSR build ----------------

__global__ void hist_kernel(const int* __restrict__ col, int* __restrict__ cnt, int e) {
    int i = blockIdx.x * blockDim.x + threadIdx.x;
    if (i < e) atomicAdd(&cnt[col[i]], 1);
}

__global__ void dinv_kernel(const int* __restrict__ cnt, float* __restrict__ dinv, int n) {
    int i = blockIdx.x * blockDim.x + threadIdx.x;
    if (i < n) dinv[i] = rsqrtf((float)(cnt[i] + 1));  // +1 self-loop
}

// exclusive scan over M=N+1 elements (cnt[i] for i<N else 0), 1024/block
__global__ void scan1_kernel(const int* __restrict__ cnt, int* __restrict__ outp,
                             int* __restrict__ bsums, int M, int n) {
    __shared__ int s[256];
    int tid = threadIdx.x;
    int base = blockIdx.x * 1024 + tid * 4;
    int v[4];
#pragma unroll
    for (int j = 0; j < 4; ++j) {
        int idx = base + j;
        v[j] = (idx < n) ? cnt[idx] : 0;
    }
    int tot = v[0] + v[1] + v[2] + v[3];
    s[tid] = tot;
    __syncthreads();
    for (int off = 1; off < 256; off <<= 1) {
        int x = (tid >= off) ? s[tid - off] : 0;
        __syncthreads();
        s[tid] += x;
        __syncthreads();
    }
    int run = (tid == 0) ? 0 : s[tid - 1];
#pragma unroll
    for (int j = 0; j < 4; ++j) {
        int idx = base + j;
        if (idx < M) outp[idx] = run;
        run += v[j];
    }
    if (tid == 255) bsums[blockIdx.x] = s[255];
}

__global__ void scan2_kernel(int* bsums, int nb) {
    if (threadIdx.x == 0 && blockIdx.x == 0) {
        int acc = 0;
        for (int i = 0; i < nb; ++i) { int v = bsums[i]; bsums[i] = acc; acc += v; }
    }
}

__global__ void scan3_kernel(int* __restrict__ outp, const int* __restrict__ bsums, int M) {
    int i = blockIdx.x * blockDim.x + threadIdx.x;
    if (i < M) outp[i] += bsums[i >> 10];
}

__global__ void place_kernel(const int* __restrict__ row, const int* __restrict__ col,
                             const float* __restrict__ dinv, const int* __restrict__ rp,
                             int* __restrict__ fill, int* __restrict__ csr_src,
                             float* __restrict__ csr_w, int e) {
    int i = blockIdx.x * blockDim.x + threadIdx.x;
    if (i < e) {
        int r = row[i], c = col[i];
        int pos = atomicAdd(&fill[c], 1);
        int idx = rp[c] + pos;
        csr_src[idx] = r;
        csr_w[idx] = dinv[r] * dinv[c];
    }
}

// ---------------- GEMM: C[n x 128] = A[n x 128] @ W[128 x 128] (+bias) ----------------
// block 256, tile 32 rows x 128 cols; thread computes 4 rows x 4 cols.
__global__ __launch_bounds__(256) void gemm128_kernel(const float* __restrict__ A,
                                                      const float* __restrict__ W,
                                                      const float* __restrict__ bias,
                                                      float* __restrict__ C, int nrows) {
    __shared__ float As[32][128];
    __shared__ float Ws[32][128];
    int tid = threadIdx.x;
    int tx = tid & 31, ty = tid >> 5;
    int rowBase = blockIdx.x * 32;

#pragma unroll
    for (int i = 0; i < 4; ++i) {
        int f = tid + i * 256;
        int r = f >> 5, cg = (f & 31) << 2;
        float4 val = make_float4(0.f, 0.f, 0.f, 0.f);
        int gr = rowBase + r;
        if (gr < nrows) val = *(const float4*)&A[gr * 128 + cg];
        *(float4*)&As[r][cg] = val;
    }

    float acc[4][4];
#pragma unroll
    for (int r = 0; r < 4; ++r)
#pragma unroll
        for (int j = 0; j < 4; ++j) acc[r][j] = 0.f;

    for (int kc = 0; kc < 4; ++kc) {
        __syncthreads();  // As ready (kc=0) / Ws reads done (kc>0)
#pragma unroll
        for (int i = 0; i < 4; ++i) {
            int f = tid + i * 256;
            int r = f >> 5, cg = (f & 31) << 2;
            *(float4*)&Ws[r][cg] = *(const float4*)&W[(kc * 32 + r) * 128 + cg];
        }
        __syncthreads();
#pragma unroll
        for (int k4 = 0; k4 < 8; ++k4) {
            float4 a[4];
#pragma unroll
            for (int r = 0; r < 4; ++r)
                a[r] = *(const float4*)&As[ty * 4 + r][kc * 32 + k4 * 4];
#pragma unroll
            for (int kk = 0; kk < 4; ++kk) {
                float4 w = *(const float4*)&Ws[k4 * 4 + kk][tx * 4];
#pragma unroll
                for (int r = 0; r < 4; ++r) {
                    float av = ((const float*)&a[r])[kk];
                    acc[r][0] += av * w.x;
                    acc[r][1] += av * w.y;
                    acc[r][2] += av * w.z;
                    acc[r][3] += av * w.w;
                }
            }
        }
    }

    float4 bv = make_float4(0.f, 0.f, 0.f, 0.f);
    if (bias) bv = *(const float4*)&bias[tx * 4];
#pragma unroll
    for (int r = 0; r < 4; ++r) {
        int gr = rowBase + ty * 4 + r;
        if (gr < nrows) {
            float4 o;
            o.x = acc[r][0] + bv.x;
            o.y = acc[r][1] + bv.y;
            o.z = acc[r][2] + bv.z;
            o.w = acc[r][3] + bv.w;
            *(float4*)&C[gr * 128 + tx * 4] = o;
        }
    }
}

// ---------------- Aggregation: agg[i] = b + dinv_i^2 * t[i] + sum_e w_e * t[src_e] ----------------
__global__ __launch_bounds__(256) void aggregate_kernel(const float* __restrict__ t,
                                                        const int* __restrict__ rp,
                                                        const int* __restrict__ src,
                                                        const float* __restrict__ w,
                                                        const float* __restrict__ dinv,
                                                        const float* __restrict__ bvec,
                                                        float* __restrict__ agg, int n) {
    int wid = blockIdx.x * 4 + (threadIdx.x >> 6);
    int lane = threadIdx.x & 63;
    if (wid >= n) return;
    int c = lane * 2;
    float di = dinv[wid];
    float sw = di * di;
    float2 tv = *(const float2*)&t[wid * 128 + c];
    float2 acc;
    acc.x = sw * tv.x + bvec[c];
    acc.y = sw * tv.y + bvec[c + 1];
    int e = rp[wid], e1 = rp[wid + 1];
    for (; e + 1 < e1; e += 2) {
        int s0 = src[e], s1 = src[e + 1];
        float w0 = w[e], w1 = w[e + 1];
        float2 t0 = *(const float2*)&t[s0 * 128 + c];
        float2 t1 = *(const float2*)&t[s1 * 128 + c];
        acc.x += w0 * t0.x + w1 * t1.x;
        acc.y += w0 * t0.y + w1 * t1.y;
    }
    if (e < e1) {
        int s0 = src[e];
        float w0 = w[e];
        float2 t0 = *(const float2*)&t[s0 * 128 + c];
        acc.x += w0 * t0.x;
        acc.y += w0 * t0.y;
    }
    *(float2*)&agg[wid * 128 + c] = acc;
}

// ---------------- BatchNorm ----------------
__global__ void bn_stats_kernel(const float* __restrict__ agg, float* __restrict__ sums, int n) {
    int tid = threadIdx.x;
    int c = tid & 127, half = tid >> 7;
    int start = blockIdx.x * 2 + half;  // 256 row-streams
    float s = 0.f, q = 0.f;
    for (int r = start; r < n; r += 256) {
        float v = agg[r * 128 + c];
        s += v;
        q += v * v;
    }
    __shared__ float ls[256], lq[256];
    ls[tid] = s;
    lq[tid] = q;
    __syncthreads();
    if (tid < 128) {
        s = ls[tid] + ls[tid + 128];
        q = lq[tid] + lq[tid + 128];
        atomicAdd(&sums[c], s);
        atomicAdd(&sums[128 + c], q);
    }
}

__global__ void bn_fin_kernel(const float* __restrict__ sums, const float* __restrict__ gamma,
                              const float* __restrict__ beta, float* __restrict__ bnp, float n) {
    int c = threadIdx.x;
    if (c < 128) {
        float mean = sums[c] / n;
        float var = sums[128 + c] / n - mean * mean;
        var = fmaxf(var, 0.f);
        float sc = gamma[c] * rsqrtf(var + BN_EPS);
        bnp[c] = sc;
        bnp[128 + c] = beta[c] - mean * sc;
    }
}

__global__ void bn_apply_kernel(const float* __restrict__ agg, const float* __restrict__ bnp,
                                float* __restrict__ h, int total4) {
    int i = blockIdx.x * blockDim.x + threadIdx.x;
    if (i >= total4) return;
    int c4 = i & 31;
    float4 v = ((const float4*)agg)[i];
    float4 sc = ((const float4*)bnp)[c4];
    float4 sh = ((const float4*)(bnp + 128))[c4];
    float4 o;
    o.x = fmaxf(v.x * sc.x + sh.x, 0.f);
    o.y = fmaxf(v.y * sc.y + sh.y, 0.f);
    o.z = fmaxf(v.z * sc.z + sh.z, 0.f);
    o.w = fmaxf(v.w * sc.w + sh.w, 0.f);
    ((float4*)h)[i] = o;
}

// ---------------- Pool + classifier ----------------
__global__ void pool_cnt_kernel(const int* __restrict__ batch, float* __restrict__ gcnt, int n) {
    int i = blockIdx.x * blockDim.x + threadIdx.x;
    if (i < n) atomicAdd(&gcnt[batch[i]], 1.0f);
}

__global__ __launch_bounds__(128) void pool_sum_kernel(const float* __restrict__ h,
                                                       const int* __restrict__ batch,
                                                       float* __restrict__ gsum, int n) {
    int c = threadIdx.x;  // 128
    int r0 = blockIdx.x * 64;
    __shared__ int sb[64];
    if (c < 64) {
        int r = r0 + c;
        sb[c] = (r < n) ? batch[r] : -1;
    }
    __syncthreads();
    int lim = n - r0;
    if (lim > 64) lim = 64;
    if (lim <= 0) return;
    int cur = sb[0];
    float acc = 0.f;
    for (int i = 0; i < lim; ++i) {
        int b = sb[i];
        if (b != cur) {
            atomicAdd(&gsum[cur * 128 + c], acc);
            acc = 0.f;
            cur = b;
        }
        acc += h[(r0 + i) * 128 + c];
    }
    atomicAdd(&gsum[cur * 128 + c], acc);
}

__global__ void cls_kernel(const float* __restrict__ gsum, const float* __restrict__ gcnt,
                           const float* __restrict__ Wc, const float* __restrict__ bc,
                           float* __restrict__ out, int nb) {
    int gid = blockIdx.x * blockDim.x + threadIdx.x;
    if (gid >= nb * NO) return;
    int b = gid / NO, o = gid - b * NO;
    float invc = 1.0f / fmaxf(gcnt[b], 1.0f);
    float s = bc[o];
    for (int c = 0; c < 128; ++c) s += gsum[b * 128 + c] * invc * Wc[c * NO + o];
    out[gid] = s;
}

// ---------------- host launch ----------------
extern "C" void kernel_launch(void* const* d_in, const int* in_sizes, int n_in,
                              void* d_out, int out_size, void* d_ws, size_t ws_size,
                              hipStream_t stream) {
    const float* x      = (const float*)d_in[0];
    const int*   eidx   = (const int*)d_in[1];
    const int*   batch  = (const int*)d_in[2];
    const float* W_enc  = (const float*)d_in[3];
    const float* b_enc  = (const float*)d_in[4];
    const float* W      = (const float*)d_in[5];
    const float* b      = (const float*)d_in[6];
    const float* gamma  = (const float*)d_in[7];
    const float* beta   = (const float*)d_in[8];
    const float* W_cls  = (const float*)d_in[9];
    const float* b_cls  = (const float*)d_in[10];
    float* out = (float*)d_out;

    const int* erow = eidx;
    const int* ecol = eidx + NE;

    // workspace layout
    float* h      = (float*)d_ws;
    float* t      = h + (size_t)NN * HD;
    float* agg    = t + (size_t)NN * HD;
    float* dinv   = agg + (size_t)NN * HD;
    float* csr_w  = dinv + NN;
    float* bnsums = csr_w + NE;        // 256
    float* bnp    = bnsums + 256;      // 256
    float* gsum   = bnp + 256;         // NB*HD
    float* gcnt   = gsum + (size_t)NB * HD;  // NB
    int* cnt      = (int*)(gcnt + NB);
    int* fill     = cnt + NN;
    int* rp       = fill + NN;         // NN+1
    int* csr_src  = rp + NN + 1;
    int* bsums    = csr_src + NE;      // 64

    hipMemsetAsync(cnt, 0, NN * sizeof(int), stream);
    hipMemsetAsync(fill, 0, NN * sizeof(int), stream);
    hipMemsetAsync(gsum, 0, (size_t)NB * HD * sizeof(float), stream);
    hipMemsetAsync(gcnt, 0, NB * sizeof(float), stream);

    // CSR build (once; reused across layers)
    hist_kernel<<<(NE + 255) / 256, 256, 0, stream>>>(ecol, cnt, NE);
    dinv_kernel<<<(NN + 255) / 256, 256, 0, stream>>>(cnt, dinv, NN);
    int M = NN + 1;
    int nscan = (M + 1023) / 1024;  // 49
    scan1_kernel<<<nscan, 256, 0, stream>>>(cnt, rp, bsums, M, NN);
    scan2_kernel<<<1, 64, 0, stream>>>(bsums, nscan);
    scan3_kernel<<<(M + 255) / 256, 256, 0, stream>>>(rp, bsums, M);
    place_kernel<<<(NE + 255) / 256, 256, 0, stream>>>(erow, ecol, dinv, rp, fill,
                                                       csr_src, csr_w, NE);

    // encoder
    int gemmBlocks = (NN + 31) / 32;
    gemm128_kernel<<<gemmBlocks, 256, 0, stream>>>(x, W_enc, b_enc, h, NN);

    for (int l = 0; l < NL; ++l) {
        gemm128_kernel<<<gemmBlocks, 256, 0, stream>>>(h, W + (size_t)l * HD * HD, nullptr, t, NN);
        aggregate_kernel<<<(NN + 3) / 4, 256, 0, stream>>>(t, rp, csr_src, csr_w, dinv,
                                                           b + (size_t)l * HD, agg, NN);
        hipMemsetAsync(bnsums, 0, 256 * sizeof(float), stream);
        bn_stats_kernel<<<128, 256, 0, stream>>>(agg, bnsums, NN);
        bn_fin_kernel<<<1, 128, 0, stream>>>(bnsums, gamma + (size_t)l * HD,
                                             beta + (size_t)l * HD, bnp, (float)NN);
        bn_apply_kernel<<<(NN * 32 + 255) / 256, 256, 0, stream>>>(agg, bnp, h, NN * 32);
    }

    pool_cnt_kernel<<<(NN + 255) / 256, 256, 0, stream>>>(batch, gcnt, NN);
    pool_sum_kernel<<<(NN + 63) / 64, 128, 0, stream>>>(h, batch, gsum, NN);
    cls_kernel<<<(NB * NO + 255) / 256, 256, 0, stream>>>(gsum, gcnt, W_cls, b_cls, out, NB);
}

// Round 2
// 682.688 us; speedup vs baseline: 1.1449x; 1.1449x over previous
//
#include <hip/hip_runtime.h>

#define NN 50000
#define NE 600000
#define HD 128
#define NL 4
#define NB 256
#define NO 10
#define BN_EPS 1e-5f

typedef short bf16x8 __attribute__((ext_vector_type(8)));
typedef float f32x4 __attribute__((ext_vector_type(4)));

__device__ __forceinline__ unsigned short f2bf(float f) {
    union { float f; unsigned int u; } x; x.f = f;
    unsigned int u = x.u;
    unsigned int r = (u + 0x7FFFu + ((u >> 16) & 1u)) >> 16;  // RNE
    return (unsigned short)r;
}
__device__ __forceinline__ float bf2f(unsigned short s) {
    union { unsigned int u; float f; } x; x.u = ((unsigned int)s) << 16;
    return x.f;
}

// ---------------- CSR build ----------------

__global__ void hist_kernel(const int* __restrict__ col, int* __restrict__ cnt, int e) {
    int i = blockIdx.x * blockDim.x + threadIdx.x;
    if (i < e) atomicAdd(&cnt[col[i]], 1);
}

__global__ void dinv_kernel(const int* __restrict__ cnt, float* __restrict__ dinv, int n) {
    int i = blockIdx.x * blockDim.x + threadIdx.x;
    if (i < n) dinv[i] = rsqrtf((float)(cnt[i] + 1));  // +1 self-loop
}

__global__ void scan1_kernel(const int* __restrict__ cnt, int* __restrict__ outp,
                             int* __restrict__ bsums, int M, int n) {
    __shared__ int s[256];
    int tid = threadIdx.x;
    int base = blockIdx.x * 1024 + tid * 4;
    int v[4];
#pragma unroll
    for (int j = 0; j < 4; ++j) {
        int idx = base + j;
        v[j] = (idx < n) ? cnt[idx] : 0;
    }
    int tot = v[0] + v[1] + v[2] + v[3];
    s[tid] = tot;
    __syncthreads();
    for (int off = 1; off < 256; off <<= 1) {
        int x = (tid >= off) ? s[tid - off] : 0;
        __syncthreads();
        s[tid] += x;
        __syncthreads();
    }
    int run = (tid == 0) ? 0 : s[tid - 1];
#pragma unroll
    for (int j = 0; j < 4; ++j) {
        int idx = base + j;
        if (idx < M) outp[idx] = run;
        run += v[j];
    }
    if (tid == 255) bsums[blockIdx.x] = s[255];
}

__global__ void scan2_kernel(int* bsums, int nb) {
    if (threadIdx.x == 0 && blockIdx.x == 0) {
        int acc = 0;
        for (int i = 0; i < nb; ++i) { int v = bsums[i]; bsums[i] = acc; acc += v; }
    }
}

__global__ void scan3_kernel(int* __restrict__ outp, const int* __restrict__ bsums, int M) {
    int i = blockIdx.x * blockDim.x + threadIdx.x;
    if (i < M) outp[i] += bsums[i >> 10];
}

__global__ void place_kernel(const int* __restrict__ row, const int* __restrict__ col,
                             const float* __restrict__ dinv, const int* __restrict__ rp,
                             int* __restrict__ fill, int* __restrict__ csr_src,
                             float* __restrict__ csr_w, int e) {
    int i = blockIdx.x * blockDim.x + threadIdx.x;
    if (i < e) {
        int r = row[i], c = col[i];
        int pos = atomicAdd(&fill[c], 1);
        int idx = rp[c] + pos;
        csr_src[idx] = r;
        csr_w[idx] = dinv[r] * dinv[c];
    }
}

// ---------------- weight transpose+convert: Wt[m][n][k] = bf16(Wsrc_m[k][n]) ----------------
__global__ void wconv_kernel(const float* __restrict__ W_enc, const float* __restrict__ W,
                             unsigned short* __restrict__ Wt) {
    int i = blockIdx.x * blockDim.x + threadIdx.x;
    if (i >= 5 * 16384) return;
    int m = i >> 14;
    int r = (i >> 7) & 127;  // dest row = n
    int k = i & 127;         // dest col = k
    const float* src = (m == 0) ? W_enc : (W + (size_t)(m - 1) * 16384);
    Wt[i] = f2bf(src[k * 128 + r]);
}

// ---------------- MFMA GEMM: C[n x 128] = A[n x 128] @ W[128 x 128] (+bias) ----------------
// A bf16 (or fp32 converted in-register), Wt = W^T bf16 [n][k]. block 256 = 4 waves,
// each wave: 16 rows x 128 cols via 8 coltiles x 4 ksteps of mfma_f32_16x16x32_bf16.
template <bool AF32, bool OB16>
__global__ __launch_bounds__(256) void gemm128_mfma(const void* __restrict__ Ap,
                                                    const unsigned short* __restrict__ Wt,
                                                    const float* __restrict__ bias,
                                                    void* __restrict__ Cp, int nrows) {
    int wave = threadIdx.x >> 6;
    int lane = threadIdx.x & 63;
    int r16 = lane & 15;
    int kg = lane >> 4;
    int rowBase = blockIdx.x * 64 + wave * 16;
    int row = rowBase + r16;
    bool valid = row < nrows;

    bf16x8 afr[4];
#pragma unroll
    for (int s = 0; s < 4; ++s) {
        if constexpr (AF32) {
            const float* A = (const float*)Ap;
            bf16x8 t = {};
            if (valid) {
                const float* p = &A[(size_t)row * 128 + s * 32 + kg * 8];
                float4 u0 = *(const float4*)p;
                float4 u1 = *(const float4*)(p + 4);
                t[0] = (short)f2bf(u0.x); t[1] = (short)f2bf(u0.y);
                t[2] = (short)f2bf(u0.z); t[3] = (short)f2bf(u0.w);
                t[4] = (short)f2bf(u1.x); t[5] = (short)f2bf(u1.y);
                t[6] = (short)f2bf(u1.z); t[7] = (short)f2bf(u1.w);
            }
            afr[s] = t;
        } else {
            const unsigned short* A = (const unsigned short*)Ap;
            bf16x8 t = {};
            if (valid) t = *(const bf16x8*)&A[(size_t)row * 128 + s * 32 + kg * 8];
            afr[s] = t;
        }
    }

    f32x4 acc[8];
#pragma unroll
    for (int n = 0; n < 8; ++n) acc[n] = (f32x4){0.f, 0.f, 0.f, 0.f};

#pragma unroll
    for (int n = 0; n < 8; ++n) {
        const unsigned short* wp = &Wt[(size_t)(n * 16 + r16) * 128 + kg * 8];
#pragma unroll
        for (int s = 0; s < 4; ++s) {
            bf16x8 bfr = *(const bf16x8*)&wp[s * 32];
            acc[n] = __builtin_amdgcn_mfma_f32_16x16x32_bf16(afr[s], bfr, acc[n], 0, 0, 0);
        }
    }

    // C/D: lane holds rows kg*4+i, col r16 (within tile)
#pragma unroll
    for (int n = 0; n < 8; ++n) {
        int col = n * 16 + r16;
        float bv = bias ? bias[col] : 0.f;
#pragma unroll
        for (int i = 0; i < 4; ++i) {
            int orow = rowBase + kg * 4 + i;
            if (orow < nrows) {
                if constexpr (OB16) {
                    ((unsigned short*)Cp)[(size_t)orow * 128 + col] = f2bf(acc[n][i] + bv);
                } else {
                    ((float*)Cp)[(size_t)orow * 128 + col] = acc[n][i] + bv;
                }
            }
        }
    }
}

// ---------------- Aggregation: agg[i] = b + dinv_i^2 * t[i] + sum_e w_e * t[src_e] ----------------
__global__ __launch_bounds__(256) void aggregate_kernel(const float* __restrict__ t,
                                                        const int* __restrict__ rp,
                                                        const int* __restrict__ src,
                                                        const float* __restrict__ w,
                                                        const float* __restrict__ dinv,
                                                        const float* __restrict__ bvec,
                                                        float* __restrict__ agg, int n) {
    int wid = blockIdx.x * 4 + (threadIdx.x >> 6);
    int lane = threadIdx.x & 63;
    if (wid >= n) return;
    int c = lane * 2;
    float di = dinv[wid];
    float sw = di * di;
    float2 tv = *(const float2*)&t[wid * 128 + c];
    float2 acc;
    acc.x = sw * tv.x + bvec[c];
    acc.y = sw * tv.y + bvec[c + 1];
    int e = rp[wid], e1 = rp[wid + 1];
    for (; e + 1 < e1; e += 2) {
        int s0 = src[e], s1 = src[e + 1];
        float w0 = w[e], w1 = w[e + 1];
        float2 t0 = *(const float2*)&t[s0 * 128 + c];
        float2 t1 = *(const float2*)&t[s1 * 128 + c];
        acc.x += w0 * t0.x + w1 * t1.x;
        acc.y += w0 * t0.y + w1 * t1.y;
    }
    if (e < e1) {
        int s0 = src[e];
        float w0 = w[e];
        float2 t0 = *(const float2*)&t[s0 * 128 + c];
        acc.x += w0 * t0.x;
        acc.y += w0 * t0.y;
    }
    *(float2*)&agg[wid * 128 + c] = acc;
}

// ---------------- BatchNorm ----------------
__global__ void bn_stats_kernel(const float* __restrict__ agg, float* __restrict__ sums, int n) {
    int tid = threadIdx.x;
    int c = tid & 127, half = tid >> 7;
    int start = blockIdx.x * 2 + half;
    float s = 0.f, q = 0.f;
    for (int r = start; r < n; r += 256) {
        float v = agg[r * 128 + c];
        s += v;
        q += v * v;
    }
    __shared__ float ls[256], lq[256];
    ls[tid] = s;
    lq[tid] = q;
    __syncthreads();
    if (tid < 128) {
        s = ls[tid] + ls[tid + 128];
        q = lq[tid] + lq[tid + 128];
        atomicAdd(&sums[c], s);
        atomicAdd(&sums[128 + c], q);
    }
}

__global__ void bn_fin_kernel(const float* __restrict__ sums, const float* __restrict__ gamma,
                              const float* __restrict__ beta, float* __restrict__ bnp, float n) {
    int c = threadIdx.x;
    if (c < 128) {
        float mean = sums[c] / n;
        float var = sums[128 + c] / n - mean * mean;
        var = fmaxf(var, 0.f);
        float sc = gamma[c] * rsqrtf(var + BN_EPS);
        bnp[c] = sc;
        bnp[128 + c] = beta[c] - mean * sc;
    }
}

// BN+ReLU, writes h as bf16
__global__ void bn_apply_kernel(const float* __restrict__ agg, const float* __restrict__ bnp,
                                unsigned short* __restrict__ h, int total4) {
    int i = blockIdx.x * blockDim.x + threadIdx.x;
    if (i >= total4) return;
    int c4 = i & 31;
    float4 v = ((const float4*)agg)[i];
    float4 sc = ((const float4*)bnp)[c4];
    float4 sh = ((const float4*)(bnp + 128))[c4];
    ushort4 o;
    o.x = f2bf(fmaxf(v.x * sc.x + sh.x, 0.f));
    o.y = f2bf(fmaxf(v.y * sc.y + sh.y, 0.f));
    o.z = f2bf(fmaxf(v.z * sc.z + sh.z, 0.f));
    o.w = f2bf(fmaxf(v.w * sc.w + sh.w, 0.f));
    ((ushort4*)h)[i] = o;
}

// ---------------- Pool + classifier ----------------
// counts per graph via binary search over sorted batch — no atomics
__global__ void graph_count_kernel(const int* __restrict__ batch, float* __restrict__ gcnt, int n) {
    int b = blockIdx.x * blockDim.x + threadIdx.x;
    if (b >= NB) return;
    int lo, hi, ub1, ub0;
    lo = 0; hi = n;
    while (lo < hi) { int mid = (lo + hi) >> 1; if (batch[mid] <= b) lo = mid + 1; else hi = mid; }
    ub1 = lo;
    lo = 0; hi = n;
    while (lo < hi) { int mid = (lo + hi) >> 1; if (batch[mid] <= b - 1) lo = mid + 1; else hi = mid; }
    ub0 = lo;
    gcnt[b] = (float)(ub1 - ub0);
}

__global__ __launch_bounds__(128) void pool_sum_kernel(const unsigned short* __restrict__ h,
                                                       const int* __restrict__ batch,
                                                       float* __restrict__ gsum, int n) {
    int c = threadIdx.x;  // 128
    int r0 = blockIdx.x * 64;
    __shared__ int sb[64];
    if (c < 64) {
        int r = r0 + c;
        sb[c] = (r < n) ? batch[r] : -1;
    }
    __syncthreads();
    int lim = n - r0;
    if (lim > 64) lim = 64;
    if (lim <= 0) return;
    int cur = sb[0];
    float acc = 0.f;
    for (int i = 0; i < lim; ++i) {
        int b = sb[i];
        if (b != cur) {
            atomicAdd(&gsum[cur * 128 + c], acc);
            acc = 0.f;
            cur = b;
        }
        acc += bf2f(h[(size_t)(r0 + i) * 128 + c]);
    }
    atomicAdd(&gsum[cur * 128 + c], acc);
}

__global__ void cls_kernel(const float* __restrict__ gsum, const float* __restrict__ gcnt,
                           const float* __restrict__ Wc, const float* __restrict__ bc,
                           float* __restrict__ out, int nb) {
    int gid = blockIdx.x * blockDim.x + threadIdx.x;
    if (gid >= nb * NO) return;
    int b = gid / NO, o = gid - b * NO;
    float invc = 1.0f / fmaxf(gcnt[b], 1.0f);
    float s = bc[o];
    for (int c = 0; c < 128; ++c) s += gsum[b * 128 + c] * invc * Wc[c * NO + o];
    out[gid] = s;
}

// ---------------- host launch ----------------
extern "C" void kernel_launch(void* const* d_in, const int* in_sizes, int n_in,
                              void* d_out, int out_size, void* d_ws, size_t ws_size,
                              hipStream_t stream) {
    const float* x      = (const float*)d_in[0];
    const int*   eidx   = (const int*)d_in[1];
    const int*   batch  = (const int*)d_in[2];
    const float* W_enc  = (const float*)d_in[3];
    const float* b_enc  = (const float*)d_in[4];
    const float* W      = (const float*)d_in[5];
    const float* b      = (const float*)d_in[6];
    const float* gamma  = (const float*)d_in[7];
    const float* beta   = (const float*)d_in[8];
    const float* W_cls  = (const float*)d_in[9];
    const float* b_cls  = (const float*)d_in[10];
    float* out = (float*)d_out;

    const int* erow = eidx;
    const int* ecol = eidx + NE;

    // workspace layout (floats)
    float* t      = (float*)d_ws;                    // NN*HD fp32
    float* agg    = t + (size_t)NN * HD;             // NN*HD fp32
    float* dinv   = agg + (size_t)NN * HD;           // NN
    float* csr_w  = dinv + NN;                       // NE
    float* bnsums = csr_w + NE;                      // 256
    float* bnp    = bnsums + 256;                    // 256
    float* gsum   = bnp + 256;                       // NB*HD
    float* gcnt   = gsum + (size_t)NB * HD;          // NB
    unsigned short* h  = (unsigned short*)(gcnt + NB);        // NN*HD bf16
    unsigned short* Wt = h + (size_t)NN * HD;                 // 5*16384 bf16
    int* cnt      = (int*)(Wt + 5 * 16384);
    int* fill     = cnt + NN;
    int* rp       = fill + NN;                       // NN+1
    int* csr_src  = rp + NN + 1;                     // NE
    int* bsums    = csr_src + NE;                    // 64

    hipMemsetAsync(cnt, 0, NN * sizeof(int), stream);
    hipMemsetAsync(fill, 0, NN * sizeof(int), stream);
    hipMemsetAsync(gsum, 0, (size_t)NB * HD * sizeof(float), stream);

    // CSR build (once; reused across layers)
    hist_kernel<<<(NE + 255) / 256, 256, 0, stream>>>(ecol, cnt, NE);
    dinv_kernel<<<(NN + 255) / 256, 256, 0, stream>>>(cnt, dinv, NN);
    int M = NN + 1;
    int nscan = (M + 1023) / 1024;
    scan1_kernel<<<nscan, 256, 0, stream>>>(cnt, rp, bsums, M, NN);
    scan2_kernel<<<1, 64, 0, stream>>>(bsums, nscan);
    scan3_kernel<<<(M + 255) / 256, 256, 0, stream>>>(rp, bsums, M);
    place_kernel<<<(NE + 255) / 256, 256, 0, stream>>>(erow, ecol, dinv, rp, fill,
                                                       csr_src, csr_w, NE);

    // weights -> bf16 transposed
    wconv_kernel<<<(5 * 16384 + 255) / 256, 256, 0, stream>>>(W_enc, W, Wt);

    int gemmBlocks = (NN + 63) / 64;
    // encoder: x fp32 -> h bf16
    gemm128_mfma<true, true><<<gemmBlocks, 256, 0, stream>>>(x, Wt, b_enc, h, NN);

    for (int l = 0; l < NL; ++l) {
        gemm128_mfma<false, false><<<gemmBlocks, 256, 0, stream>>>(
            h, Wt + (size_t)(l + 1) * 16384, nullptr, t, NN);
        aggregate_kernel<<<(NN + 3) / 4, 256, 0, stream>>>(t, rp, csr_src, csr_w, dinv,
                                                           b + (size_t)l * HD, agg, NN);
        hipMemsetAsync(bnsums, 0, 256 * sizeof(float), stream);
        bn_stats_kernel<<<128, 256, 0, stream>>>(agg, bnsums, NN);
        bn_fin_kernel<<<1, 128, 0, stream>>>(bnsums, gamma + (size_t)l * HD,
                                             beta + (size_t)l * HD, bnp, (float)NN);
        bn_apply_kernel<<<(NN * 32 + 255) / 256, 256, 0, stream>>>(agg, bnp, h, NN * 32);
    }

    graph_count_kernel<<<1, 256, 0, stream>>>(batch, gcnt, NN);
    pool_sum_kernel<<<(NN + 63) / 64, 128, 0, stream>>>(h, batch, gsum, NN);
    cls_kernel<<<(NB * NO + 255) / 256, 256, 0, stream>>>(gsum, gcnt, W_cls, b_cls, out, NB);
}

// Round 3
// 612.168 us; speedup vs baseline: 1.2768x; 1.1152x over previous
//
#include <hip/hip_runtime.h>

#define NN 50000
#define NE 600000
#define HD 128
#define NL 4
#define NB 256
#define NO 10
#define BN_EPS 1e-5f

typedef short bf16x8 __attribute__((ext_vector_type(8)));
typedef float f32x4 __attribute__((ext_vector_type(4)));

__device__ __forceinline__ unsigned short f2bf(float f) {
    union { float f; unsigned int u; } x; x.f = f;
    unsigned int u = x.u;
    unsigned int r = (u + 0x7FFFu + ((u >> 16) & 1u)) >> 16;  // RNE
    return (unsigned short)r;
}
__device__ __forceinline__ float bf2f(unsigned short s) {
    union { unsigned int u; float f; } x; x.u = ((unsigned int)s) << 16;
    return x.f;
}

// ---------------- CSR build ----------------

__global__ void hist_kernel(const int* __restrict__ col, int* __restrict__ cnt, int e) {
    int i = blockIdx.x * blockDim.x + threadIdx.x;
    if (i < e) atomicAdd(&cnt[col[i]], 1);
}

// scan over M=N+1 elements + fused dinv
__global__ void scan1_kernel(const int* __restrict__ cnt, int* __restrict__ outp,
                             int* __restrict__ bsums, float* __restrict__ dinv,
                             int M, int n) {
    __shared__ int s[256];
    int tid = threadIdx.x;
    int base = blockIdx.x * 1024 + tid * 4;
    int v[4];
#pragma unroll
    for (int j = 0; j < 4; ++j) {
        int idx = base + j;
        v[j] = (idx < n) ? cnt[idx] : 0;
        if (idx < n) dinv[idx] = rsqrtf((float)(v[j] + 1));  // +1 self-loop
    }
    int tot = v[0] + v[1] + v[2] + v[3];
    s[tid] = tot;
    __syncthreads();
    for (int off = 1; off < 256; off <<= 1) {
        int x = (tid >= off) ? s[tid - off] : 0;
        __syncthreads();
        s[tid] += x;
        __syncthreads();
    }
    int run = (tid == 0) ? 0 : s[tid - 1];
#pragma unroll
    for (int j = 0; j < 4; ++j) {
        int idx = base + j;
        if (idx < M) outp[idx] = run;
        run += v[j];
    }
    if (tid == 255) bsums[blockIdx.x] = s[255];
}

__global__ void scan2_kernel(int* bsums, int nb) {
    if (threadIdx.x == 0 && blockIdx.x == 0) {
        int acc = 0;
        for (int i = 0; i < nb; ++i) { int v = bsums[i]; bsums[i] = acc; acc += v; }
    }
}

__global__ void scan3_kernel(int* __restrict__ outp, const int* __restrict__ bsums, int M) {
    int i = blockIdx.x * blockDim.x + threadIdx.x;
    if (i < M) outp[i] += bsums[i >> 10];
}

__global__ void place_kernel(const int* __restrict__ row, const int* __restrict__ col,
                             const float* __restrict__ dinv, const int* __restrict__ rp,
                             int* __restrict__ fill, int2* __restrict__ csr, int e) {
    int i = blockIdx.x * blockDim.x + threadIdx.x;
    if (i < e) {
        int r = row[i], c = col[i];
        int pos = atomicAdd(&fill[c], 1);
        int idx = rp[c] + pos;
        csr[idx] = make_int2(r, __float_as_int(dinv[r] * dinv[c]));
    }
}

// ---------------- weight transpose+convert: Wt[m][n][k] = bf16(Wsrc_m[k][n]) ----------------
__global__ void wconv_kernel(const float* __restrict__ W_enc, const float* __restrict__ W,
                             unsigned short* __restrict__ Wt) {
    int i = blockIdx.x * blockDim.x + threadIdx.x;
    if (i >= 5 * 16384) return;
    int m = i >> 14;
    int r = (i >> 7) & 127;  // dest row = n
    int k = i & 127;         // dest col = k
    const float* src = (m == 0) ? W_enc : (W + (size_t)(m - 1) * 16384);
    Wt[i] = f2bf(src[k * 128 + r]);
}

// ---------------- MFMA GEMM: C[n x 128] = A[n x 128] @ W[128 x 128] (+bias), C bf16 ----------------
// AMODE: 0 = fp32 A, 1 = bf16 A, 2 = fp32 A with fused BN(scale,shift)+ReLU
template <int AMODE>
__global__ __launch_bounds__(256) void gemm128_mfma(const void* __restrict__ Ap,
                                                    const unsigned short* __restrict__ Wt,
                                                    const float* __restrict__ bias,
                                                    const float* __restrict__ bnp,
                                                    unsigned short* __restrict__ Cp,
                                                    int nrows) {
    int wave = threadIdx.x >> 6;
    int lane = threadIdx.x & 63;
    int r16 = lane & 15;
    int kg = lane >> 4;
    int rowBase = blockIdx.x * 64 + wave * 16;
    int row = rowBase + r16;
    bool valid = row < nrows;

    bf16x8 afr[4];
#pragma unroll
    for (int s = 0; s < 4; ++s) {
        bf16x8 tt = {};
        int c0 = s * 32 + kg * 8;
        if constexpr (AMODE == 1) {
            const unsigned short* A = (const unsigned short*)Ap;
            if (valid) tt = *(const bf16x8*)&A[(size_t)row * 128 + c0];
        } else if constexpr (AMODE == 0) {
            const float* A = (const float*)Ap;
            if (valid) {
                const float* p = &A[(size_t)row * 128 + c0];
                float4 u0 = *(const float4*)p;
                float4 u1 = *(const float4*)(p + 4);
                tt[0] = (short)f2bf(u0.x); tt[1] = (short)f2bf(u0.y);
                tt[2] = (short)f2bf(u0.z); tt[3] = (short)f2bf(u0.w);
                tt[4] = (short)f2bf(u1.x); tt[5] = (short)f2bf(u1.y);
                tt[6] = (short)f2bf(u1.z); tt[7] = (short)f2bf(u1.w);
            }
        } else {
            const float* A = (const float*)Ap;
            if (valid) {
                const float* p = &A[(size_t)row * 128 + c0];
                float4 u0 = *(const float4*)p;
                float4 u1 = *(const float4*)(p + 4);
                float4 s0 = *(const float4*)&bnp[c0];
                float4 s1 = *(const float4*)&bnp[c0 + 4];
                float4 h0 = *(const float4*)&bnp[128 + c0];
                float4 h1 = *(const float4*)&bnp[128 + c0 + 4];
                tt[0] = (short)f2bf(fmaxf(u0.x * s0.x + h0.x, 0.f));
                tt[1] = (short)f2bf(fmaxf(u0.y * s0.y + h0.y, 0.f));
                tt[2] = (short)f2bf(fmaxf(u0.z * s0.z + h0.z, 0.f));
                tt[3] = (short)f2bf(fmaxf(u0.w * s0.w + h0.w, 0.f));
                tt[4] = (short)f2bf(fmaxf(u1.x * s1.x + h1.x, 0.f));
                tt[5] = (short)f2bf(fmaxf(u1.y * s1.y + h1.y, 0.f));
                tt[6] = (short)f2bf(fmaxf(u1.z * s1.z + h1.z, 0.f));
                tt[7] = (short)f2bf(fmaxf(u1.w * s1.w + h1.w, 0.f));
            }
        }
        afr[s] = tt;
    }

    f32x4 acc[8];
#pragma unroll
    for (int n = 0; n < 8; ++n) acc[n] = (f32x4){0.f, 0.f, 0.f, 0.f};

#pragma unroll
    for (int n = 0; n < 8; ++n) {
        const unsigned short* wp = &Wt[(size_t)(n * 16 + r16) * 128 + kg * 8];
#pragma unroll
        for (int s = 0; s < 4; ++s) {
            bf16x8 bfr = *(const bf16x8*)&wp[s * 32];
            acc[n] = __builtin_amdgcn_mfma_f32_16x16x32_bf16(afr[s], bfr, acc[n], 0, 0, 0);
        }
    }

    // C/D: lane holds rows kg*4+i, col r16 (within tile)
#pragma unroll
    for (int n = 0; n < 8; ++n) {
        int col = n * 16 + r16;
        float bv = bias ? bias[col] : 0.f;
#pragma unroll
        for (int i = 0; i < 4; ++i) {
            int orow = rowBase + kg * 4 + i;
            if (orow < nrows)
                Cp[(size_t)orow * 128 + col] = f2bf(acc[n][i] + bv);
        }
    }
}

// ---------------- Aggregation: agg[i] = b + dinv_i^2 * t[i] + sum_e w_e * t[src_e] ----------------
// t is bf16; one wave per node, lane covers 2 channels (one dword/row).
__global__ __launch_bounds__(256) void aggregate_kernel(const unsigned short* __restrict__ t,
                                                        const int* __restrict__ rp,
                                                        const int2* __restrict__ csr,
                                                        const float* __restrict__ dinv,
                                                        const float* __restrict__ bvec,
                                                        float* __restrict__ agg, int n) {
    int wid = blockIdx.x * 4 + (threadIdx.x >> 6);
    int lane = threadIdx.x & 63;
    if (wid >= n) return;
    int c = lane * 2;
    float di = dinv[wid];
    float sw = di * di;
    unsigned int u = *(const unsigned int*)&t[(size_t)wid * 128 + c];
    float2 acc;
    acc.x = sw * bf2f((unsigned short)(u & 0xffff)) + bvec[c];
    acc.y = sw * bf2f((unsigned short)(u >> 16)) + bvec[c + 1];
    int e = rp[wid], e1 = rp[wid + 1];
    for (; e + 3 < e1; e += 4) {
        int2 ew0 = csr[e], ew1 = csr[e + 1], ew2 = csr[e + 2], ew3 = csr[e + 3];
        unsigned int u0 = *(const unsigned int*)&t[(size_t)ew0.x * 128 + c];
        unsigned int u1 = *(const unsigned int*)&t[(size_t)ew1.x * 128 + c];
        unsigned int u2 = *(const unsigned int*)&t[(size_t)ew2.x * 128 + c];
        unsigned int u3 = *(const unsigned int*)&t[(size_t)ew3.x * 128 + c];
        float w0 = __int_as_float(ew0.y), w1 = __int_as_float(ew1.y);
        float w2 = __int_as_float(ew2.y), w3 = __int_as_float(ew3.y);
        acc.x += w0 * bf2f((unsigned short)(u0 & 0xffff)) + w1 * bf2f((unsigned short)(u1 & 0xffff));
        acc.y += w0 * bf2f((unsigned short)(u0 >> 16)) + w1 * bf2f((unsigned short)(u1 >> 16));
        acc.x += w2 * bf2f((unsigned short)(u2 & 0xffff)) + w3 * bf2f((unsigned short)(u3 & 0xffff));
        acc.y += w2 * bf2f((unsigned short)(u2 >> 16)) + w3 * bf2f((unsigned short)(u3 >> 16));
    }
    for (; e < e1; ++e) {
        int2 ew = csr[e];
        unsigned int u0 = *(const unsigned int*)&t[(size_t)ew.x * 128 + c];
        float w0 = __int_as_float(ew.y);
        acc.x += w0 * bf2f((unsigned short)(u0 & 0xffff));
        acc.y += w0 * bf2f((unsigned short)(u0 >> 16));
    }
    *(float2*)&agg[(size_t)wid * 128 + c] = acc;
}

// ---------------- BatchNorm stats + finalize (last-block) ----------------
__global__ void bn_stats_kernel(const float* __restrict__ agg, float* __restrict__ sums,
                                int* __restrict__ counter, const float* __restrict__ gamma,
                                const float* __restrict__ beta, float* __restrict__ bnp,
                                int n) {
    int tid = threadIdx.x;
    int c = tid & 127, half = tid >> 7;
    int start = blockIdx.x * 2 + half;
    float s = 0.f, q = 0.f;
    for (int r = start; r < n; r += 256) {
        float v = agg[(size_t)r * 128 + c];
        s += v;
        q += v * v;
    }
    __shared__ float ls[256], lq[256];
    __shared__ int lastflag;
    ls[tid] = s;
    lq[tid] = q;
    __syncthreads();
    if (tid < 128) {
        s = ls[tid] + ls[tid + 128];
        q = lq[tid] + lq[tid + 128];
        atomicAdd(&sums[c], s);
        atomicAdd(&sums[128 + c], q);
    }
    __threadfence();
    __syncthreads();
    if (tid == 0) {
        int old = atomicAdd(counter, 1);
        lastflag = (old == (int)gridDim.x - 1);
    }
    __syncthreads();
    if (lastflag && tid < 128) {
        float fn = (float)n;
        float ss = atomicAdd(&sums[tid], 0.f);
        float qq = atomicAdd(&sums[128 + tid], 0.f);
        float mean = ss / fn;
        float var = fmaxf(qq / fn - mean * mean, 0.f);
        float sc = gamma[tid] * rsqrtf(var + BN_EPS);
        bnp[tid] = sc;
        bnp[128 + tid] = beta[tid] - mean * sc;
        // self-reset for next layer / next graph replay
        sums[tid] = 0.f;
        sums[128 + tid] = 0.f;
        if (tid == 0) *counter = 0;
    }
}

// ---------------- Pool (BN+ReLU fused) + classifier ----------------
__global__ __launch_bounds__(128) void pool_sum_kernel(const float* __restrict__ agg,
                                                       const float* __restrict__ bnp,
                                                       const int* __restrict__ batch,
                                                       float* __restrict__ gsum, int n) {
    int c = threadIdx.x;  // 128
    float sc = bnp[c], sh = bnp[128 + c];
    int r0 = blockIdx.x * 64;
    __shared__ int sb[64];
    if (c < 64) {
        int r = r0 + c;
        sb[c] = (r < n) ? batch[r] : -1;
    }
    __syncthreads();
    int lim = n - r0;
    if (lim > 64) lim = 64;
    if (lim <= 0) return;
    int cur = sb[0];
    float acc = 0.f;
    for (int i = 0; i < lim; ++i) {
        int b = sb[i];
        if (b != cur) {
            atomicAdd(&gsum[cur * 128 + c], acc);
            acc = 0.f;
            cur = b;
        }
        acc += fmaxf(agg[(size_t)(r0 + i) * 128 + c] * sc + sh, 0.f);
    }
    atomicAdd(&gsum[cur * 128 + c], acc);
}

// classifier with fused per-graph count (binary search over sorted batch)
__global__ void cls_kernel(const float* __restrict__ gsum, const int* __restrict__ batch,
                           const float* __restrict__ Wc, const float* __restrict__ bc,
                           float* __restrict__ out, int nb, int n) {
    int gid = blockIdx.x * blockDim.x + threadIdx.x;
    if (gid >= nb * NO) return;
    int b = gid / NO, o = gid - b * NO;
    int lo = 0, hi = n;
    while (lo < hi) { int mid = (lo + hi) >> 1; if (batch[mid] <= b) lo = mid + 1; else hi = mid; }
    int ub1 = lo;
    lo = 0; hi = n;
    while (lo < hi) { int mid = (lo + hi) >> 1; if (batch[mid] <= b - 1) lo = mid + 1; else hi = mid; }
    float cntf = (float)(ub1 - lo);
    float invc = 1.0f / fmaxf(cntf, 1.0f);
    float s = bc[o];
    for (int c = 0; c < 128; ++c) s += gsum[b * 128 + c] * invc * Wc[c * NO + o];
    out[gid] = s;
}

// ---------------- host launch ----------------
extern "C" void kernel_launch(void* const* d_in, const int* in_sizes, int n_in,
                              void* d_out, int out_size, void* d_ws, size_t ws_size,
                              hipStream_t stream) {
    const float* x      = (const float*)d_in[0];
    const int*   eidx   = (const int*)d_in[1];
    const int*   batch  = (const int*)d_in[2];
    const float* W_enc  = (const float*)d_in[3];
    const float* b_enc  = (const float*)d_in[4];
    const float* W      = (const float*)d_in[5];
    const float* b      = (const float*)d_in[6];
    const float* gamma  = (const float*)d_in[7];
    const float* beta   = (const float*)d_in[8];
    const float* W_cls  = (const float*)d_in[9];
    const float* b_cls  = (const float*)d_in[10];
    float* out = (float*)d_out;

    const int* erow = eidx;
    const int* ecol = eidx + NE;

    // workspace layout
    float* agg    = (float*)d_ws;                    // NN*HD fp32
    float* dinv   = agg + (size_t)NN * HD;           // NN
    float* bnsums = dinv + NN;                       // 256
    int*   bncnt  = (int*)(bnsums + 256);            // 4 ints (1 used)
    float* bnp    = (float*)(bncnt + 4);             // 256
    float* gsum   = bnp + 256;                       // NB*HD
    int2*  csr    = (int2*)(gsum + (size_t)NB * HD); // NE int2
    unsigned short* h  = (unsigned short*)(csr + NE);   // NN*HD bf16
    unsigned short* t  = h + (size_t)NN * HD;           // NN*HD bf16
    unsigned short* Wt = t + (size_t)NN * HD;           // 5*16384 bf16
    int* cnt      = (int*)(Wt + 5 * 16384);          // NN
    int* fill     = cnt + NN;                        // NN (adjacent -> one memset)
    int* rp       = fill + NN;                       // NN+1
    int* bsums    = rp + NN + 1;                     // 64

    hipMemsetAsync(cnt, 0, 2 * NN * sizeof(int), stream);
    hipMemsetAsync(gsum, 0, (size_t)NB * HD * sizeof(float), stream);
    hipMemsetAsync(bnsums, 0, 256 * sizeof(float) + 4 * sizeof(int), stream);

    // CSR build (once; reused across layers)
    hist_kernel<<<(NE + 255) / 256, 256, 0, stream>>>(ecol, cnt, NE);
    int M = NN + 1;
    int nscan = (M + 1023) / 1024;
    scan1_kernel<<<nscan, 256, 0, stream>>>(cnt, rp, bsums, dinv, M, NN);
    scan2_kernel<<<1, 64, 0, stream>>>(bsums, nscan);
    scan3_kernel<<<(M + 255) / 256, 256, 0, stream>>>(rp, bsums, M);
    place_kernel<<<(NE + 255) / 256, 256, 0, stream>>>(erow, ecol, dinv, rp, fill, csr, NE);

    // weights -> bf16 transposed
    wconv_kernel<<<(5 * 16384 + 255) / 256, 256, 0, stream>>>(W_enc, W, Wt);

    int gemmBlocks = (NN + 63) / 64;
    // encoder: x fp32 -> h bf16
    gemm128_mfma<0><<<gemmBlocks, 256, 0, stream>>>(x, Wt, b_enc, nullptr, h, NN);

    for (int l = 0; l < NL; ++l) {
        if (l == 0)
            gemm128_mfma<1><<<gemmBlocks, 256, 0, stream>>>(
                h, Wt + (size_t)(l + 1) * 16384, nullptr, nullptr, t, NN);
        else
            gemm128_mfma<2><<<gemmBlocks, 256, 0, stream>>>(
                agg, Wt + (size_t)(l + 1) * 16384, nullptr, bnp, t, NN);
        aggregate_kernel<<<(NN + 3) / 4, 256, 0, stream>>>(t, rp, csr, dinv,
                                                           b + (size_t)l * HD, agg, NN);
        bn_stats_kernel<<<128, 256, 0, stream>>>(agg, bnsums, bncnt,
                                                 gamma + (size_t)l * HD,
                                                 beta + (size_t)l * HD, bnp, NN);
    }

    pool_sum_kernel<<<(NN + 63) / 64, 128, 0, stream>>>(agg, bnp, batch, gsum, NN);
    cls_kernel<<<(NB * NO + 255) / 256, 256, 0, stream>>>(gsum, batch, W_cls, b_cls, out, NB, NN);
}